// Round 2
// baseline (522.261 us; speedup 1.0000x reference)
//
#include <hip/hip_runtime.h>
#include <stdint.h>

// Shapes: B=2, L=1024 -> BLT=2048 tokens; D_MODEL=512, D_INNER=1024, DT_RANK=32, D_STATE=16
#define BLT 2048
#define DMODEL 512
#define DINNER 1024

// ---------- GEMM: C[m,n] = sum_k A[m,k]*B[n,k]  (both row-major, K contiguous, f32) ----------
// 64x64 tile, BK=16, 256 threads, 4x4 register micro-tile.
__global__ __launch_bounds__(256) void gemm_nt(const float* __restrict__ A,
                                               const float* __restrict__ B,
                                               float* __restrict__ C,
                                               int M, int N, int K) {
    __shared__ float As[16][68];   // [k][m], padded (68) keeps float4 reads in-bounds/aligned
    __shared__ float Bs[16][68];   // [k][n]
    const int tid = threadIdx.x;
    const int bx = blockIdx.x, by = blockIdx.y;
    const int tx = tid & 15, ty = tid >> 4;
    const int r = tid >> 2, c4 = (tid & 3) << 2;
    float acc[4][4] = {};
    const float* ap = A + (size_t)(by * 64 + r) * K + c4;
    const float* bp = B + (size_t)(bx * 64 + r) * K + c4;
    for (int k0 = 0; k0 < K; k0 += 16, ap += 16, bp += 16) {
        float4 av = *(const float4*)ap;
        float4 bv = *(const float4*)bp;
        As[c4 + 0][r] = av.x; As[c4 + 1][r] = av.y;
        As[c4 + 2][r] = av.z; As[c4 + 3][r] = av.w;
        Bs[c4 + 0][r] = bv.x; Bs[c4 + 1][r] = bv.y;
        Bs[c4 + 2][r] = bv.z; Bs[c4 + 3][r] = bv.w;
        __syncthreads();
#pragma unroll
        for (int kk = 0; kk < 16; kk++) {
            float4 a = *(const float4*)&As[kk][ty * 4];
            float4 b = *(const float4*)&Bs[kk][tx * 4];
            float aa[4] = {a.x, a.y, a.z, a.w};
            float bb[4] = {b.x, b.y, b.z, b.w};
#pragma unroll
            for (int i = 0; i < 4; i++)
#pragma unroll
                for (int j = 0; j < 4; j++) acc[i][j] += aa[i] * bb[j];
        }
        __syncthreads();
    }
#pragma unroll
    for (int i = 0; i < 4; i++) {
        size_t off = (size_t)(by * 64 + ty * 4 + i) * N + bx * 64 + tx * 4;
        *(float4*)(C + off) = make_float4(acc[i][0], acc[i][1], acc[i][2], acc[i][3]);
    }
}

// ---------- depthwise conv1d (K=3, SAME pad over L within each batch) + SiLU ----------
__global__ __launch_bounds__(256) void conv1d_silu_k(const float* __restrict__ xz,
                                                     const float* __restrict__ w,
                                                     const float* __restrict__ bias,
                                                     float* __restrict__ xs) {
    int idx = blockIdx.x * 256 + threadIdx.x;  // t*1024 + d
    int t = idx >> 10, d = idx & 1023;
    int l = t & 1023;  // position within sequence (L=1024)
    float cur = xz[(size_t)t * 2048 + d];
    float prev = (l > 0) ? xz[(size_t)(t - 1) * 2048 + d] : 0.f;
    float nxt = (l < 1023) ? xz[(size_t)(t + 1) * 2048 + d] : 0.f;
    float v = w[d * 3] * prev + w[d * 3 + 1] * cur + w[d * 3 + 2] * nxt + bias[d];
    xs[idx] = v / (1.f + __expf(-v));  // silu
}

// ---------- x_proj (dBC) + dt_proj + softplus, one block per token ----------
__global__ __launch_bounds__(256) void xproj_dt_k(const float* __restrict__ xs,
                                                  const float* __restrict__ xpw,   // [64,1024]
                                                  const float* __restrict__ dtw,   // [1024,32]
                                                  const float* __restrict__ dtb,   // [1024]
                                                  float* __restrict__ dBC,         // [BLT,64]
                                                  float* __restrict__ delta) {     // [BLT,1024]
    __shared__ float xrow[1024];
    __shared__ float dbc[64];
    const int t = blockIdx.x, tid = threadIdx.x;
#pragma unroll
    for (int i = 0; i < 4; i++) xrow[tid + i * 256] = xs[(size_t)t * 1024 + tid + i * 256];
    __syncthreads();
    const int o = tid >> 2, sub = tid & 3;
    float p = 0.f;
    const float* wrow = xpw + o * 1024;
    for (int dd = sub; dd < 1024; dd += 4) p += xrow[dd] * wrow[dd];
    p += __shfl_xor(p, 1);
    p += __shfl_xor(p, 2);
    if (sub == 0) { dbc[o] = p; dBC[t * 64 + o] = p; }
    __syncthreads();
    const int d0 = tid * 4;
#pragma unroll
    for (int q = 0; q < 4; q++) {
        int d = d0 + q;
        float acc = dtb[d];
        const float* wr = dtw + d * 32;
#pragma unroll
        for (int rr = 0; rr < 32; rr++) acc += dbc[rr] * wr[rr];
        float sp = (acc > 20.f) ? acc : __logf(1.f + __expf(acc));  // softplus
        delta[(size_t)t * 1024 + d] = sp;
    }
}

// ---------- SSM step + 4x4 state-fusion convs + y = hn.Cm + D*xs + yz = y*silu(z) ----------
__global__ __launch_bounds__(256) void ssm_fuse_k(
    const float* __restrict__ h,       // [BLT,1024,16]
    const float* __restrict__ xz,      // [BLT,2048] (z in cols 1024..2047)
    const float* __restrict__ xs,      // [BLT,1024]
    const float* __restrict__ dBC,     // [BLT,64]
    const float* __restrict__ delta,   // [BLT,1024]
    const float* __restrict__ A_log,   // [1024,16]
    const float* __restrict__ Dp,      // [1024]
    const float* __restrict__ sf1w, const float* __restrict__ sf1b,
    const float* __restrict__ sf2w, const float* __restrict__ sf2b,
    const float* __restrict__ alpha,
    float* __restrict__ hn_out,        // [BLT,1024,16] (output 1)
    float* __restrict__ yz) {          // [BLT,1024]
    const int t = blockIdx.y;
    const int d = blockIdx.x * 256 + threadIdx.x;
    __shared__ float bc[32];  // [0..15]=Bm, [16..31]=Cm
    if (threadIdx.x < 32) bc[threadIdx.x] = dBC[t * 64 + 32 + threadIdx.x];
    __syncthreads();
    const size_t td = (size_t)t * 1024 + d;
    const float dt = delta[td], xv = xs[td];
    const float dx = dt * xv;
    float hv[16], al[16];
    const float4* hp = (const float4*)(h + td * 16);
    const float4* apv = (const float4*)(A_log + (size_t)d * 16);
#pragma unroll
    for (int q = 0; q < 4; q++) {
        float4 hq = hp[q];
        hv[q * 4 + 0] = hq.x; hv[q * 4 + 1] = hq.y; hv[q * 4 + 2] = hq.z; hv[q * 4 + 3] = hq.w;
        float4 aq = apv[q];
        al[q * 4 + 0] = aq.x; al[q * 4 + 1] = aq.y; al[q * 4 + 2] = aq.z; al[q * 4 + 3] = aq.w;
    }
    float hn[16];
#pragma unroll
    for (int s = 0; s < 16; s++) {
        float Av = -__expf(al[s]);
        hn[s] = __expf(dt * Av) * hv[s] + dx * bc[s];
    }
    // state fusion: alpha0*(1x1 dw conv) + alpha1*(3x3 dw conv, pad 1) on 4x4 grid
    const float w1 = sf1w[d], b1 = sf1b[d], b2v = sf2b[d];
    const float a0f = alpha[0], a1f = alpha[1];
    float w2[9];
#pragma unroll
    for (int k = 0; k < 9; k++) w2[k] = sf2w[d * 9 + k];
    float hf[16];
#pragma unroll
    for (int i = 0; i < 4; i++)
#pragma unroll
        for (int j = 0; j < 4; j++) {
            float s2 = b2v;
#pragma unroll
            for (int ki = 0; ki < 3; ki++)
#pragma unroll
                for (int kj = 0; kj < 3; kj++) {
                    int ii = i + ki - 1, jj = j + kj - 1;
                    if (ii >= 0 && ii < 4 && jj >= 0 && jj < 4)
                        s2 += hn[ii * 4 + jj] * w2[ki * 3 + kj];
                }
            hf[i * 4 + j] = a0f * (w1 * hn[i * 4 + j] + b1) + a1f * s2;
        }
    // y = sum_s hf[s]*Cm[s] + D*xs ; yz = y*silu(z)
    float y = Dp[d] * xv;
#pragma unroll
    for (int s = 0; s < 16; s++) y += hf[s] * bc[16 + s];
    const float zv = xz[(size_t)t * 2048 + 1024 + d];
    yz[td] = y * (zv / (1.f + __expf(-zv)));
    float4* op = (float4*)(hn_out + td * 16);
#pragma unroll
    for (int q = 0; q < 4; q++)
        op[q] = make_float4(hf[q * 4 + 0], hf[q * 4 + 1], hf[q * 4 + 2], hf[q * 4 + 3]);
}

extern "C" void kernel_launch(void* const* d_in, const int* in_sizes, int n_in,
                              void* d_out, int out_size, void* d_ws, size_t ws_size,
                              hipStream_t stream) {
    const float* x         = (const float*)d_in[0];   // [2048,512]
    const float* h         = (const float*)d_in[1];   // [2048,1024,16]
    const float* in_proj_w = (const float*)d_in[2];   // [2048,512]
    const float* conv1d_w  = (const float*)d_in[3];   // [1024,1,3]
    const float* conv1d_b  = (const float*)d_in[4];   // [1024]
    const float* x_proj_w  = (const float*)d_in[5];   // [64,1024]
    const float* dt_proj_w = (const float*)d_in[6];   // [1024,32]
    const float* dt_proj_b = (const float*)d_in[7];   // [1024]
    const float* A_log     = (const float*)d_in[8];   // [1024,16]
    const float* Dp        = (const float*)d_in[9];   // [1024]
    const float* sf1w      = (const float*)d_in[10];  // [1024]
    const float* sf1b      = (const float*)d_in[11];  // [1024]
    const float* sf2w      = (const float*)d_in[12];  // [1024,9]
    const float* sf2b      = (const float*)d_in[13];  // [1024]
    const float* alpha     = (const float*)d_in[14];  // [2]
    const float* out_projw = (const float*)d_in[15];  // [512,1024]

    float* out0   = (float*)d_out;                    // [2048,512]
    float* hn_out = out0 + (size_t)BLT * DMODEL;      // [2048,1024,16]

    // workspace layout (f32): ~40.5 MB total
    float* xz    = (float*)d_ws;                      // [2048,2048]
    float* xs    = xz + (size_t)BLT * 2048;           // [2048,1024]
    float* dBC   = xs + (size_t)BLT * DINNER;         // [2048,64]
    float* delta = dBC + (size_t)BLT * 64;            // [2048,1024]
    float* yz    = delta + (size_t)BLT * DINNER;      // [2048,1024]

    // 1) in_proj: xz = x @ in_proj_w^T   (M=2048, N=2048, K=512)
    gemm_nt<<<dim3(2048 / 64, BLT / 64), 256, 0, stream>>>(x, in_proj_w, xz, BLT, 2048, DMODEL);
    // 2) depthwise conv1d + silu -> xs
    conv1d_silu_k<<<(BLT * DINNER) / 256, 256, 0, stream>>>(xz, conv1d_w, conv1d_b, xs);
    // 3) dBC = xs @ x_proj_w^T ; delta = softplus(dBC[:, :32] @ dt_proj_w^T + dt_proj_b)
    xproj_dt_k<<<BLT, 256, 0, stream>>>(xs, x_proj_w, dt_proj_w, dt_proj_b, dBC, delta);
    // 4) SSM step + state fusion + y,z gating -> hn_out (output 1), yz
    ssm_fuse_k<<<dim3(DINNER / 256, BLT), 256, 0, stream>>>(h, xz, xs, dBC, delta, A_log, Dp,
                                                            sf1w, sf1b, sf2w, sf2b, alpha,
                                                            hn_out, yz);
    // 5) out = yz @ out_proj_w^T  (M=2048, N=512, K=1024)
    gemm_nt<<<dim3(DMODEL / 64, BLT / 64), 256, 0, stream>>>(yz, out_projw, out0,
                                                             BLT, DMODEL, DINNER);
}

// Round 3
// 422.181 us; speedup vs baseline: 1.2371x; 1.2371x over previous
//
#include <hip/hip_runtime.h>
#include <stdint.h>

// Shapes: B=2, L=1024 -> BLT=2048 tokens; D_MODEL=512, D_INNER=1024, DT_RANK=32, D_STATE=16
#define BLT 2048
#define DMODEL 512
#define DINNER 1024

typedef __bf16 bf16x8 __attribute__((ext_vector_type(8)));
typedef float f32x4 __attribute__((ext_vector_type(4)));

// ---------------- MFMA GEMM: C[m,n] = sum_k A[m,k] * B[n,k], f32 in/out ----------------
// BM=128, BK=64, BN in {128, 64}. 256 threads = 4 waves arranged 2x2.
// Wave tile: 64 x (BN/2). MFMA 16x16x32 bf16. f32 -> bf16 conversion in staging.
// Fragment layouts (HW-verified, learn_hip m89/m91/m120):
//   A/B operand: elem[m_or_n = lane&15][k = (lane>>4)*8 + j], j=0..7 (8 contiguous k)
//   C/D:         col(n) = lane&15, row(m) = (lane>>4)*4 + reg
template <int BN>
__global__ __launch_bounds__(256) void gemm_mfma(const float* __restrict__ A,
                                                 const float* __restrict__ B,
                                                 float* __restrict__ C,
                                                 int M, int N, int K) {
    __shared__ __bf16 As[128][72];   // 72 = 64 + 8 pad: row stride 144B (16B-aligned, conflict-light)
    __shared__ __bf16 Bs[BN][72];
    const int tid = threadIdx.x;
    const int wave = tid >> 6, lane = tid & 63;
    const int waveM = wave >> 1, waveN = wave & 1;
    const int quad = lane >> 4, l16 = lane & 15;
    constexpr int WN = BN / 2;       // wave N extent
    constexpr int NI = WN / 16;      // MFMA tiles along N per wave
    const int m0 = blockIdx.y * 128, n0 = blockIdx.x * BN;

    f32x4 acc[4][NI];
#pragma unroll
    for (int mi = 0; mi < 4; mi++)
#pragma unroll
        for (int ni = 0; ni < NI; ni++) acc[mi][ni] = (f32x4){0.f, 0.f, 0.f, 0.f};

    const int sr = tid >> 4;          // staging row base (0..15)
    const int sc = (tid & 15) * 4;    // staging col (float4 granularity over BK=64)

    for (int k0 = 0; k0 < K; k0 += 64) {
        // stage A: 128 rows x 64 k (8 passes of 16 rows)
#pragma unroll
        for (int p = 0; p < 8; p++) {
            int r = sr + p * 16;
            float4 v = *(const float4*)(A + (size_t)(m0 + r) * K + k0 + sc);
            union { __bf16 b[4]; uint2 u; } pk;
            pk.b[0] = (__bf16)v.x; pk.b[1] = (__bf16)v.y;
            pk.b[2] = (__bf16)v.z; pk.b[3] = (__bf16)v.w;
            *(uint2*)&As[r][sc] = pk.u;
        }
        // stage B: BN rows x 64 k
#pragma unroll
        for (int p = 0; p < BN / 16; p++) {
            int r = sr + p * 16;
            float4 v = *(const float4*)(B + (size_t)(n0 + r) * K + k0 + sc);
            union { __bf16 b[4]; uint2 u; } pk;
            pk.b[0] = (__bf16)v.x; pk.b[1] = (__bf16)v.y;
            pk.b[2] = (__bf16)v.z; pk.b[3] = (__bf16)v.w;
            *(uint2*)&Bs[r][sc] = pk.u;
        }
        __syncthreads();
#pragma unroll
        for (int kk = 0; kk < 64; kk += 32) {
            bf16x8 af[4], bfr[NI];
#pragma unroll
            for (int mi = 0; mi < 4; mi++)
                af[mi] = *(const bf16x8*)&As[waveM * 64 + mi * 16 + l16][kk + quad * 8];
#pragma unroll
            for (int ni = 0; ni < NI; ni++)
                bfr[ni] = *(const bf16x8*)&Bs[waveN * WN + ni * 16 + l16][kk + quad * 8];
#pragma unroll
            for (int mi = 0; mi < 4; mi++)
#pragma unroll
                for (int ni = 0; ni < NI; ni++)
                    acc[mi][ni] = __builtin_amdgcn_mfma_f32_16x16x32_bf16(
                        af[mi], bfr[ni], acc[mi][ni], 0, 0, 0);
        }
        __syncthreads();
    }
    // epilogue: row m = quad*4+reg, col n = l16 within each 16x16 tile
#pragma unroll
    for (int mi = 0; mi < 4; mi++)
#pragma unroll
        for (int ni = 0; ni < NI; ni++)
#pragma unroll
            for (int reg = 0; reg < 4; reg++) {
                int m = m0 + waveM * 64 + mi * 16 + quad * 4 + reg;
                int n = n0 + waveN * WN + ni * 16 + l16;
                C[(size_t)m * N + n] = acc[mi][ni][reg];
            }
}

// ---------- depthwise conv1d (K=3, SAME pad over L within each batch) + SiLU ----------
__global__ __launch_bounds__(256) void conv1d_silu_k(const float* __restrict__ xz,
                                                     const float* __restrict__ w,
                                                     const float* __restrict__ bias,
                                                     float* __restrict__ xs) {
    int idx = blockIdx.x * 256 + threadIdx.x;  // t*1024 + d
    int t = idx >> 10, d = idx & 1023;
    int l = t & 1023;  // position within sequence (L=1024)
    float cur = xz[(size_t)t * 2048 + d];
    float prev = (l > 0) ? xz[(size_t)(t - 1) * 2048 + d] : 0.f;
    float nxt = (l < 1023) ? xz[(size_t)(t + 1) * 2048 + d] : 0.f;
    float v = w[d * 3] * prev + w[d * 3 + 1] * cur + w[d * 3 + 2] * nxt + bias[d];
    xs[idx] = v / (1.f + __expf(-v));  // silu
}

// ---- SSM step (with fused dt_proj+softplus) + 4x4 state convs + y.Cm + D*xs + y*silu(z) ----
// grid: (4, BLT); block 256. d = blockIdx.x*256 + tid.
__global__ __launch_bounds__(256) void ssm_fuse_k(
    const float* __restrict__ h,       // [BLT,1024,16]
    const float* __restrict__ xz,      // [BLT,2048] (z in cols 1024..2047)
    const float* __restrict__ xs,      // [BLT,1024]
    const float* __restrict__ dBC,     // [BLT,64]  (0:32 dt-rank, 32:48 B, 48:64 C)
    const float* __restrict__ dtw,     // [1024,32]
    const float* __restrict__ dtb,     // [1024]
    const float* __restrict__ A_log,   // [1024,16]
    const float* __restrict__ Dp,      // [1024]
    const float* __restrict__ sf1w, const float* __restrict__ sf1b,
    const float* __restrict__ sf2w, const float* __restrict__ sf2b,
    const float* __restrict__ alpha,
    float* __restrict__ hn_out,        // [BLT,1024,16] (output 1)
    float* __restrict__ yz) {          // [BLT,1024]
    const int tid = threadIdx.x;
    const int t = blockIdx.y;
    const int dq = blockIdx.x;
    const int d = dq * 256 + tid;
    __shared__ float dbc_s[64];
    __shared__ float dtw_s[256][33];   // +1 pad: lane-distinct banks on [tid][r] reads
    if (tid < 64) dbc_s[tid] = dBC[t * 64 + tid];
    {
        const float* wsrc = dtw + (size_t)dq * 256 * 32;
#pragma unroll
        for (int j = 0; j < 8; j++) {
            int f = tid + j * 256;     // float4 index over 2048
            float4 v = *(const float4*)(wsrc + (size_t)f * 4);
            int row = f >> 3, c = (f & 7) * 4;
            dtw_s[row][c] = v.x; dtw_s[row][c + 1] = v.y;
            dtw_s[row][c + 2] = v.z; dtw_s[row][c + 3] = v.w;
        }
    }
    __syncthreads();
    // delta = softplus(dBC[:, :32] @ dtw^T + dtb)
    float accd = dtb[d];
#pragma unroll
    for (int r = 0; r < 32; r++) accd += dbc_s[r] * dtw_s[tid][r];
    const float dt = (accd > 20.f) ? accd : __logf(1.f + __expf(accd));

    const size_t td = (size_t)t * 1024 + d;
    const float xv = xs[td];
    const float dx = dt * xv;
    float hv[16], al[16];
    const float4* hp = (const float4*)(h + td * 16);
    const float4* apv = (const float4*)(A_log + (size_t)d * 16);
#pragma unroll
    for (int q = 0; q < 4; q++) {
        float4 hq = hp[q];
        hv[q * 4 + 0] = hq.x; hv[q * 4 + 1] = hq.y; hv[q * 4 + 2] = hq.z; hv[q * 4 + 3] = hq.w;
        float4 aq = apv[q];
        al[q * 4 + 0] = aq.x; al[q * 4 + 1] = aq.y; al[q * 4 + 2] = aq.z; al[q * 4 + 3] = aq.w;
    }
    float hn[16];
#pragma unroll
    for (int s = 0; s < 16; s++) {
        float Av = -__expf(al[s]);
        hn[s] = __expf(dt * Av) * hv[s] + dx * dbc_s[32 + s];
    }
    // state fusion: alpha0*(1x1 dw conv) + alpha1*(3x3 dw conv, pad 1) on 4x4 grid
    const float w1 = sf1w[d], b1 = sf1b[d], b2v = sf2b[d];
    const float a0f = alpha[0], a1f = alpha[1];
    float w2[9];
#pragma unroll
    for (int k = 0; k < 9; k++) w2[k] = sf2w[d * 9 + k];
    float hf[16];
#pragma unroll
    for (int i = 0; i < 4; i++)
#pragma unroll
        for (int j = 0; j < 4; j++) {
            float s2 = b2v;
#pragma unroll
            for (int ki = 0; ki < 3; ki++)
#pragma unroll
                for (int kj = 0; kj < 3; kj++) {
                    int ii = i + ki - 1, jj = j + kj - 1;
                    if (ii >= 0 && ii < 4 && jj >= 0 && jj < 4)
                        s2 += hn[ii * 4 + jj] * w2[ki * 3 + kj];
                }
            hf[i * 4 + j] = a0f * (w1 * hn[i * 4 + j] + b1) + a1f * s2;
        }
    // y = sum_s hf[s]*Cm[s] + D*xs ; yz = y*silu(z)
    float y = Dp[d] * xv;
#pragma unroll
    for (int s = 0; s < 16; s++) y += hf[s] * dbc_s[48 + s];
    const float zv = xz[(size_t)t * 2048 + 1024 + d];
    yz[td] = y * (zv / (1.f + __expf(-zv)));
    float4* op = (float4*)(hn_out + td * 16);
#pragma unroll
    for (int q = 0; q < 4; q++)
        op[q] = make_float4(hf[q * 4 + 0], hf[q * 4 + 1], hf[q * 4 + 2], hf[q * 4 + 3]);
}

extern "C" void kernel_launch(void* const* d_in, const int* in_sizes, int n_in,
                              void* d_out, int out_size, void* d_ws, size_t ws_size,
                              hipStream_t stream) {
    const float* x         = (const float*)d_in[0];   // [2048,512]
    const float* h         = (const float*)d_in[1];   // [2048,1024,16]
    const float* in_proj_w = (const float*)d_in[2];   // [2048,512]
    const float* conv1d_w  = (const float*)d_in[3];   // [1024,1,3]
    const float* conv1d_b  = (const float*)d_in[4];   // [1024]
    const float* x_proj_w  = (const float*)d_in[5];   // [64,1024]
    const float* dt_proj_w = (const float*)d_in[6];   // [1024,32]
    const float* dt_proj_b = (const float*)d_in[7];   // [1024]
    const float* A_log     = (const float*)d_in[8];   // [1024,16]
    const float* Dp        = (const float*)d_in[9];   // [1024]
    const float* sf1w      = (const float*)d_in[10];  // [1024]
    const float* sf1b      = (const float*)d_in[11];  // [1024]
    const float* sf2w      = (const float*)d_in[12];  // [1024,9]
    const float* sf2b      = (const float*)d_in[13];  // [1024]
    const float* alpha     = (const float*)d_in[14];  // [2]
    const float* out_projw = (const float*)d_in[15];  // [512,1024]

    float* out0   = (float*)d_out;                    // [2048,512]
    float* hn_out = out0 + (size_t)BLT * DMODEL;      // [2048,1024,16]

    // workspace layout (f32): ~34 MB total
    float* xz  = (float*)d_ws;                        // [2048,2048]
    float* xs  = xz + (size_t)BLT * 2048;             // [2048,1024]
    float* dBC = xs + (size_t)BLT * DINNER;           // [2048,64]
    float* yz  = dBC + (size_t)BLT * 64;              // [2048,1024]

    // 1) in_proj: xz = x @ in_proj_w^T   (M=2048, N=2048, K=512) — MFMA bf16
    gemm_mfma<128><<<dim3(2048 / 128, BLT / 128), 256, 0, stream>>>(x, in_proj_w, xz,
                                                                    BLT, 2048, DMODEL);
    // 2) depthwise conv1d + silu -> xs
    conv1d_silu_k<<<(BLT * DINNER) / 256, 256, 0, stream>>>(xz, conv1d_w, conv1d_b, xs);
    // 3) dBC = xs @ x_proj_w^T (M=2048, N=64, K=1024) — MFMA bf16
    gemm_mfma<64><<<dim3(1, BLT / 128), 256, 0, stream>>>(xs, x_proj_w, dBC, BLT, 64, DINNER);
    // 4) fused dt_proj+softplus + SSM step + state fusion + gating -> hn_out, yz
    ssm_fuse_k<<<dim3(4, BLT), 256, 0, stream>>>(h, xz, xs, dBC, dt_proj_w, dt_proj_b,
                                                 A_log, Dp, sf1w, sf1b, sf2w, sf2b, alpha,
                                                 hn_out, yz);
    // 5) out = yz @ out_proj_w^T  (M=2048, N=512, K=1024) — MFMA bf16
    gemm_mfma<128><<<dim3(DMODEL / 128, BLT / 128), 256, 0, stream>>>(yz, out_projw, out0,
                                                                      BLT, DMODEL, DINNER);
}

// Round 4
// 403.102 us; speedup vs baseline: 1.2956x; 1.0473x over previous
//
#include <hip/hip_runtime.h>
#include <stdint.h>

// Shapes: B=2, L=1024 -> BLT=2048 tokens; D_MODEL=512, D_INNER=1024, DT_RANK=32, D_STATE=16
#define BLT 2048
#define DMODEL 512
#define DINNER 1024

typedef __bf16 bf16x8 __attribute__((ext_vector_type(8)));
typedef float f32x4 __attribute__((ext_vector_type(4)));

// ---------------- MFMA GEMM: C[m,n] = sum_k A[m,k] * B[n,k], f32 in/out ----------------
// BM=128, BN=128, BK=64. 256 threads = 4 waves arranged 2x2, wave tile 64x64.
__global__ __launch_bounds__(256) void gemm_mfma(const float* __restrict__ A,
                                                 const float* __restrict__ B,
                                                 float* __restrict__ C,
                                                 int M, int N, int K) {
    __shared__ __bf16 As[128][72];
    __shared__ __bf16 Bs[128][72];
    const int tid = threadIdx.x;
    const int wave = tid >> 6, lane = tid & 63;
    const int waveM = wave >> 1, waveN = wave & 1;
    const int quad = lane >> 4, l16 = lane & 15;
    const int m0 = blockIdx.y * 128, n0 = blockIdx.x * 128;

    f32x4 acc[4][4];
#pragma unroll
    for (int mi = 0; mi < 4; mi++)
#pragma unroll
        for (int ni = 0; ni < 4; ni++) acc[mi][ni] = (f32x4){0.f, 0.f, 0.f, 0.f};

    const int sr = tid >> 4;
    const int sc = (tid & 15) * 4;

    for (int k0 = 0; k0 < K; k0 += 64) {
#pragma unroll
        for (int p = 0; p < 8; p++) {
            int r = sr + p * 16;
            float4 v = *(const float4*)(A + (size_t)(m0 + r) * K + k0 + sc);
            union { __bf16 b[4]; uint2 u; } pk;
            pk.b[0] = (__bf16)v.x; pk.b[1] = (__bf16)v.y;
            pk.b[2] = (__bf16)v.z; pk.b[3] = (__bf16)v.w;
            *(uint2*)&As[r][sc] = pk.u;
        }
#pragma unroll
        for (int p = 0; p < 8; p++) {
            int r = sr + p * 16;
            float4 v = *(const float4*)(B + (size_t)(n0 + r) * K + k0 + sc);
            union { __bf16 b[4]; uint2 u; } pk;
            pk.b[0] = (__bf16)v.x; pk.b[1] = (__bf16)v.y;
            pk.b[2] = (__bf16)v.z; pk.b[3] = (__bf16)v.w;
            *(uint2*)&Bs[r][sc] = pk.u;
        }
        __syncthreads();
#pragma unroll
        for (int kk = 0; kk < 64; kk += 32) {
            bf16x8 af[4], bfr[4];
#pragma unroll
            for (int mi = 0; mi < 4; mi++)
                af[mi] = *(const bf16x8*)&As[waveM * 64 + mi * 16 + l16][kk + quad * 8];
#pragma unroll
            for (int ni = 0; ni < 4; ni++)
                bfr[ni] = *(const bf16x8*)&Bs[waveN * 64 + ni * 16 + l16][kk + quad * 8];
#pragma unroll
            for (int mi = 0; mi < 4; mi++)
#pragma unroll
                for (int ni = 0; ni < 4; ni++)
                    acc[mi][ni] = __builtin_amdgcn_mfma_f32_16x16x32_bf16(
                        af[mi], bfr[ni], acc[mi][ni], 0, 0, 0);
        }
        __syncthreads();
    }
#pragma unroll
    for (int mi = 0; mi < 4; mi++)
#pragma unroll
        for (int ni = 0; ni < 4; ni++)
#pragma unroll
            for (int reg = 0; reg < 4; reg++) {
                int m = m0 + waveM * 64 + mi * 16 + quad * 4 + reg;
                int n = n0 + waveN * 64 + ni * 16 + l16;
                C[(size_t)m * N + n] = acc[mi][ni][reg];
            }
}

// ---------------- small-M MFMA GEMM: BM=32, BN=64 (for the skinny dBC GEMM) ----------------
// 4 waves arranged 2(M) x 2(N); wave tile 16x32.
__global__ __launch_bounds__(256) void gemm_mfma_s(const float* __restrict__ A,
                                                   const float* __restrict__ B,
                                                   float* __restrict__ C,
                                                   int M, int N, int K) {
    __shared__ __bf16 As[32][72];
    __shared__ __bf16 Bs[64][72];
    const int tid = threadIdx.x;
    const int wave = tid >> 6, lane = tid & 63;
    const int waveM = wave >> 1, waveN = wave & 1;
    const int quad = lane >> 4, l16 = lane & 15;
    const int m0 = blockIdx.y * 32, n0 = blockIdx.x * 64;

    f32x4 acc[2];
    acc[0] = (f32x4){0.f, 0.f, 0.f, 0.f};
    acc[1] = (f32x4){0.f, 0.f, 0.f, 0.f};

    const int sr = tid >> 4;
    const int sc = (tid & 15) * 4;

    for (int k0 = 0; k0 < K; k0 += 64) {
#pragma unroll
        for (int p = 0; p < 2; p++) {
            int r = sr + p * 16;
            float4 v = *(const float4*)(A + (size_t)(m0 + r) * K + k0 + sc);
            union { __bf16 b[4]; uint2 u; } pk;
            pk.b[0] = (__bf16)v.x; pk.b[1] = (__bf16)v.y;
            pk.b[2] = (__bf16)v.z; pk.b[3] = (__bf16)v.w;
            *(uint2*)&As[r][sc] = pk.u;
        }
#pragma unroll
        for (int p = 0; p < 4; p++) {
            int r = sr + p * 16;
            float4 v = *(const float4*)(B + (size_t)(n0 + r) * K + k0 + sc);
            union { __bf16 b[4]; uint2 u; } pk;
            pk.b[0] = (__bf16)v.x; pk.b[1] = (__bf16)v.y;
            pk.b[2] = (__bf16)v.z; pk.b[3] = (__bf16)v.w;
            *(uint2*)&Bs[r][sc] = pk.u;
        }
        __syncthreads();
#pragma unroll
        for (int kk = 0; kk < 64; kk += 32) {
            bf16x8 af = *(const bf16x8*)&As[waveM * 16 + l16][kk + quad * 8];
#pragma unroll
            for (int ni = 0; ni < 2; ni++) {
                bf16x8 bf = *(const bf16x8*)&Bs[waveN * 32 + ni * 16 + l16][kk + quad * 8];
                acc[ni] = __builtin_amdgcn_mfma_f32_16x16x32_bf16(af, bf, acc[ni], 0, 0, 0);
            }
        }
        __syncthreads();
    }
#pragma unroll
    for (int ni = 0; ni < 2; ni++)
#pragma unroll
        for (int reg = 0; reg < 4; reg++) {
            int m = m0 + waveM * 16 + quad * 4 + reg;
            int n = n0 + waveN * 32 + ni * 16 + l16;
            C[(size_t)m * N + n] = acc[ni][reg];
        }
}

// ---------- prep: dtwT[r][d] = dtw[d][r] ; Aneg = -exp(A_log) ----------
__global__ __launch_bounds__(256) void prep_k(const float* __restrict__ dtw,   // [1024,32]
                                              const float* __restrict__ A_log, // [1024,16]
                                              float* __restrict__ dtwT,        // [32,1024]
                                              float* __restrict__ Aneg) {      // [1024,16]
    int i = blockIdx.x * 256 + threadIdx.x;  // grid 128 -> 32768 threads
    {   // dtwT: 32768 elems
        int r = i >> 10, d = i & 1023;
        dtwT[i] = dtw[d * 32 + r];
    }
    if (i < 16384) Aneg[i] = -__expf(A_log[i]);
}

// ---------- depthwise conv1d (K=3, SAME pad over L within each batch) + SiLU ----------
__global__ __launch_bounds__(256) void conv1d_silu_k(const float* __restrict__ xz,
                                                     const float* __restrict__ w,
                                                     const float* __restrict__ bias,
                                                     float* __restrict__ xs) {
    int idx = blockIdx.x * 256 + threadIdx.x;  // t*1024 + d
    int t = idx >> 10, d = idx & 1023;
    int l = t & 1023;
    float cur = xz[(size_t)t * 2048 + d];
    float prev = (l > 0) ? xz[(size_t)(t - 1) * 2048 + d] : 0.f;
    float nxt = (l < 1023) ? xz[(size_t)(t + 1) * 2048 + d] : 0.f;
    float v = w[d * 3] * prev + w[d * 3 + 1] * cur + w[d * 3 + 2] * nxt + bias[d];
    xs[idx] = v / (1.f + __expf(-v));
}

// ---- SSM step (inline dt_proj via dtwT) + 4x4 state convs + y.Cm + D*xs + y*silu(z) ----
__global__ __launch_bounds__(256) void ssm_fuse_k(
    const float* __restrict__ h,       // [BLT,1024,16]
    const float* __restrict__ xz,      // [BLT,2048] (z in cols 1024..2047)
    const float* __restrict__ xs,      // [BLT,1024]
    const float* __restrict__ dBC,     // [BLT,64]  (0:32 dt-rank, 32:48 B, 48:64 C)
    const float* __restrict__ dtwT,    // [32,1024]
    const float* __restrict__ dtb,     // [1024]
    const float* __restrict__ Aneg,    // [1024,16]
    const float* __restrict__ Dp,      // [1024]
    const float* __restrict__ sf1w, const float* __restrict__ sf1b,
    const float* __restrict__ sf2w, const float* __restrict__ sf2b,
    const float* __restrict__ alpha,
    float* __restrict__ hn_out,        // [BLT,1024,16] (output 1)
    float* __restrict__ yz) {          // [BLT,1024]
    const int tid = threadIdx.x;
    const int t = blockIdx.y;
    const int d = blockIdx.x * 256 + tid;
    __shared__ float dbc_s[64];
    if (tid < 64) dbc_s[tid] = dBC[t * 64 + tid];
    __syncthreads();
    // delta = softplus(dBC[:, :32] @ dtw^T + dtb) — dtwT reads are coalesced & L2-resident
    float accd = dtb[d];
#pragma unroll
    for (int r = 0; r < 32; r++) accd += dbc_s[r] * dtwT[r * 1024 + d];
    const float dt = (accd > 20.f) ? accd : __logf(1.f + __expf(accd));

    const size_t td = (size_t)t * 1024 + d;
    const float xv = xs[td];
    const float dx = dt * xv;
    float hv[16], an[16];
    const float4* hp = (const float4*)(h + td * 16);
    const float4* apv = (const float4*)(Aneg + (size_t)d * 16);
#pragma unroll
    for (int q = 0; q < 4; q++) {
        float4 hq = hp[q];
        hv[q * 4 + 0] = hq.x; hv[q * 4 + 1] = hq.y; hv[q * 4 + 2] = hq.z; hv[q * 4 + 3] = hq.w;
        float4 aq = apv[q];
        an[q * 4 + 0] = aq.x; an[q * 4 + 1] = aq.y; an[q * 4 + 2] = aq.z; an[q * 4 + 3] = aq.w;
    }
    float hn[16];
#pragma unroll
    for (int s = 0; s < 16; s++)
        hn[s] = __expf(dt * an[s]) * hv[s] + dx * dbc_s[32 + s];
    // state fusion: alpha0*(1x1 dw conv) + alpha1*(3x3 dw conv, pad 1) on 4x4 grid
    const float w1 = sf1w[d], b1 = sf1b[d], b2v = sf2b[d];
    const float a0f = alpha[0], a1f = alpha[1];
    float w2[9];
#pragma unroll
    for (int k = 0; k < 9; k++) w2[k] = sf2w[d * 9 + k];
    float hf[16];
#pragma unroll
    for (int i = 0; i < 4; i++)
#pragma unroll
        for (int j = 0; j < 4; j++) {
            float s2 = b2v;
#pragma unroll
            for (int ki = 0; ki < 3; ki++)
#pragma unroll
                for (int kj = 0; kj < 3; kj++) {
                    int ii = i + ki - 1, jj = j + kj - 1;
                    if (ii >= 0 && ii < 4 && jj >= 0 && jj < 4)
                        s2 += hn[ii * 4 + jj] * w2[ki * 3 + kj];
                }
            hf[i * 4 + j] = a0f * (w1 * hn[i * 4 + j] + b1) + a1f * s2;
        }
    float y = Dp[d] * xv;
#pragma unroll
    for (int s = 0; s < 16; s++) y += hf[s] * dbc_s[48 + s];
    const float zv = xz[(size_t)t * 2048 + 1024 + d];
    yz[td] = y * (zv / (1.f + __expf(-zv)));
    float4* op = (float4*)(hn_out + td * 16);
#pragma unroll
    for (int q = 0; q < 4; q++)
        op[q] = make_float4(hf[q * 4 + 0], hf[q * 4 + 1], hf[q * 4 + 2], hf[q * 4 + 3]);
}

extern "C" void kernel_launch(void* const* d_in, const int* in_sizes, int n_in,
                              void* d_out, int out_size, void* d_ws, size_t ws_size,
                              hipStream_t stream) {
    const float* x         = (const float*)d_in[0];
    const float* h         = (const float*)d_in[1];
    const float* in_proj_w = (const float*)d_in[2];
    const float* conv1d_w  = (const float*)d_in[3];
    const float* conv1d_b  = (const float*)d_in[4];
    const float* x_proj_w  = (const float*)d_in[5];
    const float* dt_proj_w = (const float*)d_in[6];
    const float* dt_proj_b = (const float*)d_in[7];
    const float* A_log     = (const float*)d_in[8];
    const float* Dp        = (const float*)d_in[9];
    const float* sf1w      = (const float*)d_in[10];
    const float* sf1b      = (const float*)d_in[11];
    const float* sf2w      = (const float*)d_in[12];
    const float* sf2b      = (const float*)d_in[13];
    const float* alpha     = (const float*)d_in[14];
    const float* out_projw = (const float*)d_in[15];

    float* out0   = (float*)d_out;                    // [2048,512]
    float* hn_out = out0 + (size_t)BLT * DMODEL;      // [2048,1024,16]

    // workspace (f32): ~34.5 MB
    float* xz   = (float*)d_ws;                       // [2048,2048]
    float* xs   = xz + (size_t)BLT * 2048;            // [2048,1024]
    float* dBC  = xs + (size_t)BLT * DINNER;          // [2048,64]
    float* yz   = dBC + (size_t)BLT * 64;             // [2048,1024]
    float* dtwT = yz + (size_t)BLT * DINNER;          // [32,1024]
    float* Aneg = dtwT + 32 * 1024;                   // [1024,16]

    // 0) prep: dtw transpose + Aneg = -exp(A_log)
    prep_k<<<128, 256, 0, stream>>>(dt_proj_w, A_log, dtwT, Aneg);
    // 1) in_proj: xz = x @ in_proj_w^T   (M=2048, N=2048, K=512)
    gemm_mfma<<<dim3(2048 / 128, BLT / 128), 256, 0, stream>>>(x, in_proj_w, xz,
                                                               BLT, 2048, DMODEL);
    // 2) depthwise conv1d + silu -> xs
    conv1d_silu_k<<<(BLT * DINNER) / 256, 256, 0, stream>>>(xz, conv1d_w, conv1d_b, xs);
    // 3) dBC = xs @ x_proj_w^T (M=2048, N=64, K=1024) — 64 blocks now
    gemm_mfma_s<<<dim3(1, BLT / 32), 256, 0, stream>>>(xs, x_proj_w, dBC, BLT, 64, DINNER);
    // 4) SSM step + state fusion + gating -> hn_out, yz
    ssm_fuse_k<<<dim3(4, BLT), 256, 0, stream>>>(h, xz, xs, dBC, dtwT, dt_proj_b,
                                                 Aneg, Dp, sf1w, sf1b, sf2w, sf2b, alpha,
                                                 hn_out, yz);
    // 5) out = yz @ out_proj_w^T  (M=2048, N=512, K=1024)
    gemm_mfma<<<dim3(DMODEL / 128, BLT / 128), 256, 0, stream>>>(yz, out_projw, out0,
                                                                 BLT, DMODEL, DINNER);
}